// Round 7
// baseline (119.662 us; speedup 1.0000x reference)
//
#include <hip/hip_runtime.h>
#include <hip/hip_bf16.h>

namespace {

typedef unsigned short u16;
typedef __attribute__((ext_vector_type(8))) short bf16x8;
typedef __attribute__((ext_vector_type(4))) float f32x4;

constexpr int kB = 8, kT = 2048, kC = 1024, kH = 64;
constexpr float kScale = 0.03125f;  // 1024^-0.5

// workspace layout in u16 elements
constexpr size_t kWtOff = 0;                                 // 3*64*1024
constexpr size_t kQbOff = kWtOff + 3 * 64 * 1024;            // 16384*64
constexpr size_t kKbOff = kQbOff + (size_t)16384 * 64;
constexpr size_t kVtOff = kKbOff + (size_t)16384 * 64;       // v^T [b*64+h][t]
constexpr size_t kLOff  = kVtOff + (size_t)16384 * 64;       // float l[16384]

__device__ __forceinline__ u16 f2bu(float f) {
  __hip_bfloat16 h = __float2bfloat16(f);
  return *reinterpret_cast<u16*>(&h);
}
__device__ __forceinline__ float bu2f(unsigned int u) {
  union { unsigned int i; float f; } w;
  w.i = u << 16;
  return w.f;
}
__device__ __forceinline__ f32x4 mfma16(bf16x8 a, bf16x8 b, f32x4 c) {
  return __builtin_amdgcn_mfma_f32_16x16x32_bf16(a, b, c, 0, 0, 0);
}

// K0: Wt[mat][h][c] = bf16(W[c][h])
__global__ __launch_bounds__(256) void wt_kernel(
    const float* __restrict__ Wk, const float* __restrict__ Wq,
    const float* __restrict__ Wv, u16* __restrict__ Wt) {
  __shared__ float wsm[64 * 65];
  const int c0 = blockIdx.x * 64;
  const int mat = blockIdx.y;
  const float* W = (mat == 0) ? Wk : (mat == 1) ? Wq : Wv;
  const int tid = threadIdx.x;
#pragma unroll
  for (int ii = 0; ii < 4; ++ii) {
    const int p = tid + 256 * ii;
    const int row = p >> 4, col4 = p & 15;
    const float4 wv = *reinterpret_cast<const float4*>(&W[(size_t)(c0 + row) * 64 + col4 * 4]);
    wsm[row * 65 + col4 * 4 + 0] = wv.x;
    wsm[row * 65 + col4 * 4 + 1] = wv.y;
    wsm[row * 65 + col4 * 4 + 2] = wv.z;
    wsm[row * 65 + col4 * 4 + 3] = wv.w;
  }
  __syncthreads();
  const int h = tid & 63, seg = tid >> 6;
#pragma unroll
  for (int i = 0; i < 16; ++i) {
    const int c = seg * 16 + i;
    Wt[((size_t)mat * 64 + h) * 1024 + c0 + c] = f2bu(wsm[c * 65 + h]);
  }
}

// K1: fused q,k,v GEMM. 4-wave blocks, M-tile 16 shared, N-split by wave.
// K staged in 256-wide phases (dbuf 16x256 bf16 LDS); ONE barrier per phase.
// Phase: issue 4 x-loads early -> 8 K-steps {LDS A-frag, 3 W-frags, 3 MFMA}
// -> convert+write stage -> barrier.  24 MFMA + 24 L2 loads between barriers.
__global__ __launch_bounds__(256) void qkv_kernel(
    const float* __restrict__ x, const u16* __restrict__ Wt,
    u16* __restrict__ qb, u16* __restrict__ kb, u16* __restrict__ vt) {
  __shared__ u16 xs[2][16 * 256];  // 2 x 8 KiB, XOR-swizzled (bits 3-5 by row&7)
  const int tid = threadIdx.x;
  const int lane = tid & 63, w = tid >> 6;
  const int l15 = lane & 15, l4 = lane >> 4;
  const int m0 = blockIdx.x * 16;

  f32x4 acc[3];
#pragma unroll
  for (int mat = 0; mat < 3; ++mat) acc[mat] = f32x4{0.f, 0.f, 0.f, 0.f};

  const u16* wbase = Wt + (size_t)(w * 16 + l15) * 1024 + 8 * l4;

  // staging map: chunk p = tid + 256*jj -> row = p>>6, col = (p&63)*4
  int srow[4], sidx[4];
  const float* xrow[4];
#pragma unroll
  for (int jj = 0; jj < 4; ++jj) {
    const int p = tid + 256 * jj;
    srow[jj] = p >> 6;
    const int c = (p & 63) * 4;
    sidx[jj] = (srow[jj] * 256 + c) ^ ((srow[jj] & 7) << 3);
    xrow[jj] = x + (size_t)(m0 + srow[jj]) * kC + c;
  }

  // prologue: stage phase 0
  float4 xr[4];
#pragma unroll
  for (int jj = 0; jj < 4; ++jj) xr[jj] = *reinterpret_cast<const float4*>(xrow[jj]);
#pragma unroll
  for (int jj = 0; jj < 4; ++jj) {
    uint2 pk;
    pk.x = (unsigned)f2bu(xr[jj].x) | ((unsigned)f2bu(xr[jj].y) << 16);
    pk.y = (unsigned)f2bu(xr[jj].z) | ((unsigned)f2bu(xr[jj].w) << 16);
    *reinterpret_cast<uint2*>(&xs[0][sidx[jj]]) = pk;
  }
  __syncthreads();

  for (int p = 0; p < 4; ++p) {
    // issue next phase's global loads early (latency hidden under compute)
    if (p < 3) {
#pragma unroll
      for (int jj = 0; jj < 4; ++jj)
        xr[jj] = *reinterpret_cast<const float4*>(xrow[jj] + (p + 1) * 256);
    }
    const u16* xb = xs[p & 1];
    const int kp = p * 256;
    bf16x8 wf[3];
#pragma unroll
    for (int mat = 0; mat < 3; ++mat)
      wf[mat] = *reinterpret_cast<const bf16x8*>(wbase + (size_t)mat * 65536 + kp);
#pragma unroll
    for (int ks = 0; ks < 8; ++ks) {
      const bf16x8 a = *reinterpret_cast<const bf16x8*>(
          &xb[(l15 * 256 + ks * 32 + 8 * l4) ^ ((l15 & 7) << 3)]);
      bf16x8 wn[3];
      if (ks < 7) {
#pragma unroll
        for (int mat = 0; mat < 3; ++mat)
          wn[mat] = *reinterpret_cast<const bf16x8*>(
              wbase + (size_t)mat * 65536 + kp + (ks + 1) * 32);
      }
#pragma unroll
      for (int mat = 0; mat < 3; ++mat) acc[mat] = mfma16(a, wf[mat], acc[mat]);
      if (ks < 7) {
#pragma unroll
        for (int mat = 0; mat < 3; ++mat) wf[mat] = wn[mat];
      }
    }
    // write-late: stage next phase, then publish
    if (p < 3) {
#pragma unroll
      for (int jj = 0; jj < 4; ++jj) {
        uint2 pk;
        pk.x = (unsigned)f2bu(xr[jj].x) | ((unsigned)f2bu(xr[jj].y) << 16);
        pk.y = (unsigned)f2bu(xr[jj].z) | ((unsigned)f2bu(xr[jj].w) << 16);
        *reinterpret_cast<uint2*>(&xs[(p + 1) & 1][sidx[jj]]) = pk;
      }
    }
    __syncthreads();
  }

  const int hcol = w * 16 + l15;
#pragma unroll
  for (int mat = 0; mat < 3; ++mat) {
#pragma unroll
    for (int r = 0; r < 4; ++r) {
      const int m = m0 + 4 * l4 + r;
      const u16 val = f2bu(acc[mat][r]);
      if (mat == 0) kb[(size_t)m * 64 + hcol] = val;
      else if (mat == 1) qb[(size_t)m * 64 + hcol] = val;
      else vt[((size_t)((m >> 11) * 64 + hcol)) * 2048 + (m & 2047)] = val;
    }
  }
}

// K2: l[b,s] = sum_{t>=s} exp(scale * q_t.k_s).  mfma(A=K, B=Q) -> D[s][t].
__global__ __launch_bounds__(256) void colsum_kernel(
    const u16* __restrict__ qb, const u16* __restrict__ kb, float* __restrict__ lG) {
  const int s0 = blockIdx.x * 64;
  const int tc = blockIdx.y * 512;
  const int b = blockIdx.z;
  if (tc + 511 < s0) return;
  const int tid = threadIdx.x;
  const int lane = tid & 63, w = tid >> 6;
  const int l15 = lane & 15, l4 = lane >> 4;

  bf16x8 ka[4][2];
#pragma unroll
  for (int i = 0; i < 4; ++i) {
    const u16* kp = kb + (size_t)(b * kT + s0 + 16 * i + l15) * 64 + 8 * l4;
    ka[i][0] = *reinterpret_cast<const bf16x8*>(kp);
    ka[i][1] = *reinterpret_cast<const bf16x8*>(kp + 32);
  }
  f32x4 cs[4];
#pragma unroll
  for (int i = 0; i < 4; ++i) cs[i] = f32x4{0.f, 0.f, 0.f, 0.f};

  const int d0 = s0 - tc - 128 * w;
  const int jstart = (d0 > 0) ? (d0 >> 4) : 0;
  const u16* qbase = qb + (size_t)(b * kT + tc + 128 * w + l15) * 64 + 8 * l4;
  bf16x8 qf0, qf1;
  if (jstart < 8) {
    qf0 = *reinterpret_cast<const bf16x8*>(qbase + (size_t)jstart * 1024);
    qf1 = *reinterpret_cast<const bf16x8*>(qbase + (size_t)jstart * 1024 + 32);
  }
  for (int j = jstart; j < 8; ++j) {
    bf16x8 qn0, qn1;
    if (j < 7) {
      qn0 = *reinterpret_cast<const bf16x8*>(qbase + (size_t)(j + 1) * 1024);
      qn1 = *reinterpret_cast<const bf16x8*>(qbase + (size_t)(j + 1) * 1024 + 32);
    }
    const int t = tc + 128 * w + 16 * j + l15;
#pragma unroll
    for (int i = 0; i < 4; ++i) {
      f32x4 d = f32x4{0.f, 0.f, 0.f, 0.f};
      d = mfma16(ka[i][0], qf0, d);
      d = mfma16(ka[i][1], qf1, d);
#pragma unroll
      for (int r = 0; r < 4; ++r) {
        const int s = s0 + 16 * i + 4 * l4 + r;
        if (t >= s) cs[i][r] += __expf(d[r] * kScale);
      }
    }
    qf0 = qn0; qf1 = qn1;
  }
#pragma unroll
  for (int i = 0; i < 4; ++i) {
#pragma unroll
    for (int r = 0; r < 4; ++r) {
      float v = cs[i][r];
      v += __shfl_xor(v, 1, 64);
      v += __shfl_xor(v, 2, 64);
      v += __shfl_xor(v, 4, 64);
      v += __shfl_xor(v, 8, 64);
      if (l15 == 0) atomicAdd(&lG[b * kT + s0 + 16 * i + 4 * l4 + r], v);
    }
  }
}

// K2.5: vt[b*64+h][s] *= 1/l[b][s]
__global__ __launch_bounds__(256) void vscale_kernel(
    u16* __restrict__ vt, const float* __restrict__ lG) {
  const int idx = blockIdx.x * 256 + threadIdx.x;
  const int row = idx >> 8;
  const int tc = (idx & 255) * 8;
  const int b = row >> 6;
  u16* vp = vt + (size_t)row * 2048 + tc;
  uint4 pv = *reinterpret_cast<const uint4*>(vp);
  const float* lp = lG + b * 2048 + tc;
  const float4 la = *reinterpret_cast<const float4*>(lp);
  const float4 lb = *reinterpret_cast<const float4*>(lp + 4);
  uint4 ov;
  ov.x = (unsigned)f2bu(bu2f(pv.x & 0xffffu) / la.x) |
         ((unsigned)f2bu(bu2f(pv.x >> 16) / la.y) << 16);
  ov.y = (unsigned)f2bu(bu2f(pv.y & 0xffffu) / la.z) |
         ((unsigned)f2bu(bu2f(pv.y >> 16) / la.w) << 16);
  ov.z = (unsigned)f2bu(bu2f(pv.z & 0xffffu) / lb.x) |
         ((unsigned)f2bu(bu2f(pv.z >> 16) / lb.y) << 16);
  ov.w = (unsigned)f2bu(bu2f(pv.w & 0xffffu) / lb.z) |
         ((unsigned)f2bu(bu2f(pv.w >> 16) / lb.w) << 16);
  *reinterpret_cast<uint4*>(vp) = ov;
}

// K3: out[t,h] = sum_{s<=t} exp(scale*q.k) * vhat[s,h].
// Block = t-tile pair (x, 127-x), 8 waves (512 thr) share the t-tile,
// s-striped by 8; k-frags prefetched; vhat-frags issued early.
// Deterministic 8-way LDS reduce, single coalesced store, no atomics.
__global__ __launch_bounds__(512) void out_kernel(
    const u16* __restrict__ qb, const u16* __restrict__ kb, const u16* __restrict__ vt,
    float* __restrict__ out) {
  __shared__ u16 pl[8][1024];       // per-wave P tile, XOR-swizzled (16 KiB)
  __shared__ float red[8][16][64];  // per-wave partial output (32 KiB)
  const int pr = blockIdx.x;        // 0..63
  const int b = blockIdx.y;
  const int tid = threadIdx.x;
  const int lane = tid & 63, w = tid >> 6;
  const int l15 = lane & 15, l4 = lane >> 4;
  const size_t bT = (size_t)b * kT;

#pragma unroll
  for (int half = 0; half < 2; ++half) {
    const int tt = half ? (127 - pr) : pr;
    const int t0 = tt * 16;
    const u16* qp = qb + (bT + t0 + l15) * 64 + 8 * l4;
    const bf16x8 qf0 = *reinterpret_cast<const bf16x8*>(qp);
    const bf16x8 qf1 = *reinterpret_cast<const bf16x8*>(qp + 32);

    f32x4 acc[4];
#pragma unroll
    for (int nf = 0; nf < 4; ++nf) acc[nf] = f32x4{0.f, 0.f, 0.f, 0.f};

    const int njs = (t0 + 15) / 64 + 1;
    bf16x8 kf[4][2];
    int js = w;
    if (js < njs) {
      const int s0 = js * 64;
#pragma unroll
      for (int jf = 0; jf < 4; ++jf) {
        const u16* kp = kb + (bT + s0 + 16 * jf + l15) * 64 + 8 * l4;
        kf[jf][0] = *reinterpret_cast<const bf16x8*>(kp);
        kf[jf][1] = *reinterpret_cast<const bf16x8*>(kp + 32);
      }
    }
    for (; js < njs; js += 8) {
      const int s0 = js * 64;
      // vhat frags: issued now, consumed after the P LDS round-trip
      bf16x8 vf[4][2];
#pragma unroll
      for (int nf = 0; nf < 4; ++nf) {
        const u16* vp = vt + (size_t)(b * 64 + 16 * nf + l15) * kT + s0 + 8 * l4;
        vf[nf][0] = *reinterpret_cast<const bf16x8*>(vp);
        vf[nf][1] = *reinterpret_cast<const bf16x8*>(vp + 32);
      }
      // QK^T -> P -> wave-private LDS
#pragma unroll
      for (int jf = 0; jf < 4; ++jf) {
        f32x4 d = f32x4{0.f, 0.f, 0.f, 0.f};
        d = mfma16(qf0, kf[jf][0], d);
        d = mfma16(qf1, kf[jf][1], d);
        const int s = s0 + 16 * jf + l15;
#pragma unroll
        for (int r = 0; r < 4; ++r) {
          const int rr = 4 * l4 + r;
          const float p = (t0 + rr >= s) ? __expf(d[r] * kScale) : 0.f;
          pl[w][(rr * 64 + 16 * jf + l15) ^ ((rr & 7) << 3)] = f2bu(p);
        }
      }
      // prefetch next iteration's k-frags
      const int jn = js + 8;
      if (jn < njs) {
        const int sn = jn * 64;
#pragma unroll
        for (int jf = 0; jf < 4; ++jf) {
          const u16* kp = kb + (bT + sn + 16 * jf + l15) * 64 + 8 * l4;
          kf[jf][0] = *reinterpret_cast<const bf16x8*>(kp);
          kf[jf][1] = *reinterpret_cast<const bf16x8*>(kp + 32);
        }
      }
      // PV
      const bf16x8 pa0 = *reinterpret_cast<const bf16x8*>(
          &pl[w][(l15 * 64 + 8 * l4) ^ ((l15 & 7) << 3)]);
      const bf16x8 pa1 = *reinterpret_cast<const bf16x8*>(
          &pl[w][(l15 * 64 + 32 + 8 * l4) ^ ((l15 & 7) << 3)]);
#pragma unroll
      for (int nf = 0; nf < 4; ++nf) {
        acc[nf] = mfma16(pa0, vf[nf][0], acc[nf]);
        acc[nf] = mfma16(pa1, vf[nf][1], acc[nf]);
      }
    }
    // deterministic cross-wave reduce
#pragma unroll
    for (int nf = 0; nf < 4; ++nf) {
#pragma unroll
      for (int r = 0; r < 4; ++r) red[w][4 * l4 + r][16 * nf + l15] = acc[nf][r];
    }
    __syncthreads();
#pragma unroll
    for (int i = 0; i < 2; ++i) {
      const int idx = tid + 512 * i;
      const int r = idx >> 6, h = idx & 63;
      float sum = red[0][r][h];
#pragma unroll
      for (int ww = 1; ww < 8; ++ww) sum += red[ww][r][h];
      out[(bT + t0 + r) * 64 + h] = sum;
    }
    __syncthreads();  // protect red before next half rewrites it
  }
}

}  // namespace

extern "C" void kernel_launch(void* const* d_in, const int* in_sizes, int n_in,
                              void* d_out, int out_size, void* d_ws, size_t ws_size,
                              hipStream_t stream) {
  const float* x = (const float*)d_in[0];
  const float* Wk = (const float*)d_in[1];
  const float* Wq = (const float*)d_in[2];
  const float* Wv = (const float*)d_in[3];
  u16* wsu = (u16*)d_ws;
  u16* Wt = wsu + kWtOff;
  u16* qb = wsu + kQbOff;
  u16* kb = wsu + kKbOff;
  u16* vt = wsu + kVtOff;
  float* lG = (float*)(wsu + kLOff);
  float* out = (float*)d_out;

  hipMemsetAsync(lG, 0, kB * kT * sizeof(float), stream);
  wt_kernel<<<dim3(16, 3), dim3(256), 0, stream>>>(Wk, Wq, Wv, Wt);
  qkv_kernel<<<dim3(kB * kT / 16), dim3(256), 0, stream>>>(x, Wt, qb, kb, vt);
  colsum_kernel<<<dim3(kT / 64, 4, kB), dim3(256), 0, stream>>>(qb, kb, lG);
  vscale_kernel<<<dim3(512), dim3(256), 0, stream>>>(vt, lG);
  out_kernel<<<dim3(64, kB), dim3(512), 0, stream>>>(qb, kb, vt, out);
}

// Round 8
// 88.098 us; speedup vs baseline: 1.3583x; 1.3583x over previous
//
#include <hip/hip_runtime.h>
#include <hip/hip_bf16.h>

namespace {

typedef unsigned short u16;
typedef __attribute__((ext_vector_type(8))) short bf16x8;
typedef __attribute__((ext_vector_type(4))) float f32x4;

constexpr int kB = 8, kT = 2048, kC = 1024, kH = 64;
constexpr float kScale = 0.03125f;  // 1024^-0.5

// workspace layout in u16 elements
constexpr size_t kWtOff = 0;                                 // 3*64*1024
constexpr size_t kQbOff = kWtOff + 3 * 64 * 1024;            // 16384*64
constexpr size_t kKbOff = kQbOff + (size_t)16384 * 64;
constexpr size_t kVtOff = kKbOff + (size_t)16384 * 64;       // v^T [b*64+h][t]
constexpr size_t kLOff  = kVtOff + (size_t)16384 * 64;       // float l[16384]

__device__ __forceinline__ u16 f2bu(float f) {
  __hip_bfloat16 h = __float2bfloat16(f);
  return *reinterpret_cast<u16*>(&h);
}
__device__ __forceinline__ float bu2f(unsigned int u) {
  union { unsigned int i; float f; } w;
  w.i = u << 16;
  return w.f;
}
__device__ __forceinline__ f32x4 mfma16(bf16x8 a, bf16x8 b, f32x4 c) {
  return __builtin_amdgcn_mfma_f32_16x16x32_bf16(a, b, c, 0, 0, 0);
}

// K0: Wt[mat][h][c] = bf16(W[c][h])  (rows indexed by ncol = mat*64+h)
__global__ __launch_bounds__(256) void wt_kernel(
    const float* __restrict__ Wk, const float* __restrict__ Wq,
    const float* __restrict__ Wv, u16* __restrict__ Wt) {
  __shared__ float wsm[64 * 65];
  const int c0 = blockIdx.x * 64;
  const int mat = blockIdx.y;
  const float* W = (mat == 0) ? Wk : (mat == 1) ? Wq : Wv;
  const int tid = threadIdx.x;
#pragma unroll
  for (int ii = 0; ii < 4; ++ii) {
    const int p = tid + 256 * ii;
    const int row = p >> 4, col4 = p & 15;
    const float4 wv = *reinterpret_cast<const float4*>(&W[(size_t)(c0 + row) * 64 + col4 * 4]);
    wsm[row * 65 + col4 * 4 + 0] = wv.x;
    wsm[row * 65 + col4 * 4 + 1] = wv.y;
    wsm[row * 65 + col4 * 4 + 2] = wv.z;
    wsm[row * 65 + col4 * 4 + 3] = wv.w;
  }
  __syncthreads();
  const int h = tid & 63, seg = tid >> 6;
#pragma unroll
  for (int i = 0; i < 16; ++i) {
    const int c = seg * 16 + i;
    Wt[((size_t)mat * 64 + h) * 1024 + c0 + c] = f2bu(wsm[c * 65 + h]);
  }
}

// K1: fused q,k,v GEMM.  BM=32 (512 blocks = 2/CU), 4 waves, 8 K-phases of 128.
// Per phase: cooperative bulk-fill of W[192][128] + x[32][128] into swizzled
// LDS (16 deep-queued 16B loads/thread), then pure-LDS MFMA (24/wave).
// Wave w owns N-cols [48w, 48w+48); A-frags shared across waves.
__global__ __launch_bounds__(256) void qkv_kernel(
    const float* __restrict__ x, const u16* __restrict__ Wt,
    u16* __restrict__ qb, u16* __restrict__ kb, u16* __restrict__ vt) {
  __shared__ u16 wl[192 * 128];  // 48 KiB, XOR-swizzled (u16-idx bits 3-5 ^ row&7)
  __shared__ u16 xl[32 * 128];   // 8 KiB, same swizzle
  const int tid = threadIdx.x;
  const int lane = tid & 63, w = tid >> 6;
  const int l15 = lane & 15, l4 = lane >> 4;
  const int m0 = blockIdx.x * 32;

  f32x4 acc[2][3];
#pragma unroll
  for (int mi = 0; mi < 2; ++mi)
#pragma unroll
    for (int ni = 0; ni < 3; ++ni) acc[mi][ni] = f32x4{0.f, 0.f, 0.f, 0.f};

  for (int p = 0; p < 8; ++p) {
    const int k0 = p * 128;
    __syncthreads();  // previous compute done reading LDS
    // fill W-slice: 192 rows x 128 k, 12 x 16B per thread
#pragma unroll
    for (int i = 0; i < 12; ++i) {
      const int q = tid + 256 * i;
      const int row = q >> 4, c8 = (q & 15) * 8;
      const uint4 wv = *reinterpret_cast<const uint4*>(&Wt[(size_t)row * 1024 + k0 + c8]);
      *reinterpret_cast<uint4*>(&wl[(row * 128 + c8) ^ ((row & 7) << 3)]) = wv;
    }
    // fill x-slice: 32 rows x 128 k (f32 -> bf16), 4 x 16B loads per thread
#pragma unroll
    for (int i = 0; i < 4; ++i) {
      const int q = tid + 256 * i;
      const int row = q >> 5, c4 = (q & 31) * 4;
      const float4 xv = *reinterpret_cast<const float4*>(&x[(size_t)(m0 + row) * kC + k0 + c4]);
      uint2 pk;
      pk.x = (unsigned)f2bu(xv.x) | ((unsigned)f2bu(xv.y) << 16);
      pk.y = (unsigned)f2bu(xv.z) | ((unsigned)f2bu(xv.w) << 16);
      *reinterpret_cast<uint2*>(&xl[(row * 128 + c4) ^ ((row & 7) << 3)]) = pk;
    }
    __syncthreads();  // fill visible
#pragma unroll
    for (int ks = 0; ks < 4; ++ks) {
      const int kk = ks * 32 + 8 * l4;
      bf16x8 a[2];
#pragma unroll
      for (int mi = 0; mi < 2; ++mi) {
        const int row = 16 * mi + l15;
        a[mi] = *reinterpret_cast<const bf16x8*>(&xl[(row * 128 + kk) ^ ((row & 7) << 3)]);
      }
#pragma unroll
      for (int ni = 0; ni < 3; ++ni) {
        const int row = 48 * w + 16 * ni + l15;
        const bf16x8 bfr =
            *reinterpret_cast<const bf16x8*>(&wl[(row * 128 + kk) ^ ((row & 7) << 3)]);
#pragma unroll
        for (int mi = 0; mi < 2; ++mi) acc[mi][ni] = mfma16(a[mi], bfr, acc[mi][ni]);
      }
    }
  }
  // store: D row = 4*l4 + r (+16*mi), col ncol = 48w + 16ni + l15 (mat uniform/frag)
#pragma unroll
  for (int ni = 0; ni < 3; ++ni) {
    const int ncol = 48 * w + 16 * ni + l15;
    const int mat = ncol >> 6, h = ncol & 63;
#pragma unroll
    for (int mi = 0; mi < 2; ++mi) {
#pragma unroll
      for (int r = 0; r < 4; ++r) {
        const int m = m0 + 16 * mi + 4 * l4 + r;
        const u16 val = f2bu(acc[mi][ni][r]);
        if (mat == 0) kb[(size_t)m * 64 + h] = val;
        else if (mat == 1) qb[(size_t)m * 64 + h] = val;
        else vt[((size_t)((m >> 11) * 64 + h)) * 2048 + (m & 2047)] = val;
      }
    }
  }
}

// K2: l[b,s] = sum_{t>=s} exp(scale * q_t.k_s).  mfma(A=K, B=Q) -> D[s][t].
__global__ __launch_bounds__(256) void colsum_kernel(
    const u16* __restrict__ qb, const u16* __restrict__ kb, float* __restrict__ lG) {
  const int s0 = blockIdx.x * 64;
  const int tc = blockIdx.y * 512;
  const int b = blockIdx.z;
  if (tc + 511 < s0) return;
  const int tid = threadIdx.x;
  const int lane = tid & 63, w = tid >> 6;
  const int l15 = lane & 15, l4 = lane >> 4;

  bf16x8 ka[4][2];
#pragma unroll
  for (int i = 0; i < 4; ++i) {
    const u16* kp = kb + (size_t)(b * kT + s0 + 16 * i + l15) * 64 + 8 * l4;
    ka[i][0] = *reinterpret_cast<const bf16x8*>(kp);
    ka[i][1] = *reinterpret_cast<const bf16x8*>(kp + 32);
  }
  f32x4 cs[4];
#pragma unroll
  for (int i = 0; i < 4; ++i) cs[i] = f32x4{0.f, 0.f, 0.f, 0.f};

  const int d0 = s0 - tc - 128 * w;
  const int jstart = (d0 > 0) ? (d0 >> 4) : 0;
  const u16* qbase = qb + (size_t)(b * kT + tc + 128 * w + l15) * 64 + 8 * l4;
  bf16x8 qf0, qf1;
  if (jstart < 8) {
    qf0 = *reinterpret_cast<const bf16x8*>(qbase + (size_t)jstart * 1024);
    qf1 = *reinterpret_cast<const bf16x8*>(qbase + (size_t)jstart * 1024 + 32);
  }
  for (int j = jstart; j < 8; ++j) {
    bf16x8 qn0, qn1;
    if (j < 7) {
      qn0 = *reinterpret_cast<const bf16x8*>(qbase + (size_t)(j + 1) * 1024);
      qn1 = *reinterpret_cast<const bf16x8*>(qbase + (size_t)(j + 1) * 1024 + 32);
    }
    const int t = tc + 128 * w + 16 * j + l15;
#pragma unroll
    for (int i = 0; i < 4; ++i) {
      f32x4 d = f32x4{0.f, 0.f, 0.f, 0.f};
      d = mfma16(ka[i][0], qf0, d);
      d = mfma16(ka[i][1], qf1, d);
#pragma unroll
      for (int r = 0; r < 4; ++r) {
        const int s = s0 + 16 * i + 4 * l4 + r;
        if (t >= s) cs[i][r] += __expf(d[r] * kScale);
      }
    }
    qf0 = qn0; qf1 = qn1;
  }
#pragma unroll
  for (int i = 0; i < 4; ++i) {
#pragma unroll
    for (int r = 0; r < 4; ++r) {
      float v = cs[i][r];
      v += __shfl_xor(v, 1, 64);
      v += __shfl_xor(v, 2, 64);
      v += __shfl_xor(v, 4, 64);
      v += __shfl_xor(v, 8, 64);
      if (l15 == 0) atomicAdd(&lG[b * kT + s0 + 16 * i + 4 * l4 + r], v);
    }
  }
}

// K2.5: vt[b*64+h][s] *= 1/l[b][s]
__global__ __launch_bounds__(256) void vscale_kernel(
    u16* __restrict__ vt, const float* __restrict__ lG) {
  const int idx = blockIdx.x * 256 + threadIdx.x;
  const int row = idx >> 8;
  const int tc = (idx & 255) * 8;
  const int b = row >> 6;
  u16* vp = vt + (size_t)row * 2048 + tc;
  uint4 pv = *reinterpret_cast<const uint4*>(vp);
  const float* lp = lG + b * 2048 + tc;
  const float4 la = *reinterpret_cast<const float4*>(lp);
  const float4 lb = *reinterpret_cast<const float4*>(lp + 4);
  uint4 ov;
  ov.x = (unsigned)f2bu(bu2f(pv.x & 0xffffu) / la.x) |
         ((unsigned)f2bu(bu2f(pv.x >> 16) / la.y) << 16);
  ov.y = (unsigned)f2bu(bu2f(pv.y & 0xffffu) / la.z) |
         ((unsigned)f2bu(bu2f(pv.y >> 16) / la.w) << 16);
  ov.z = (unsigned)f2bu(bu2f(pv.z & 0xffffu) / lb.x) |
         ((unsigned)f2bu(bu2f(pv.z >> 16) / lb.y) << 16);
  ov.w = (unsigned)f2bu(bu2f(pv.w & 0xffffu) / lb.z) |
         ((unsigned)f2bu(bu2f(pv.w >> 16) / lb.w) << 16);
  *reinterpret_cast<uint4*>(vp) = ov;
}

// K3: out[t,h] = sum_{s<=t} exp(scale*q.k) * vhat[s,h].
// Block = t-tile pair (x, 127-x), 8 waves share the t-tile, s-striped by 8.
// Deterministic 8-way LDS reduce, single coalesced store, no atomics.
__global__ __launch_bounds__(512) void out_kernel(
    const u16* __restrict__ qb, const u16* __restrict__ kb, const u16* __restrict__ vt,
    float* __restrict__ out) {
  __shared__ u16 pl[8][1024];       // per-wave P tile, XOR-swizzled (16 KiB)
  __shared__ float red[8][16][64];  // per-wave partial output (32 KiB)
  const int pr = blockIdx.x;        // 0..63
  const int b = blockIdx.y;
  const int tid = threadIdx.x;
  const int lane = tid & 63, w = tid >> 6;
  const int l15 = lane & 15, l4 = lane >> 4;
  const size_t bT = (size_t)b * kT;

#pragma unroll
  for (int half = 0; half < 2; ++half) {
    const int tt = half ? (127 - pr) : pr;
    const int t0 = tt * 16;
    const u16* qp = qb + (bT + t0 + l15) * 64 + 8 * l4;
    const bf16x8 qf0 = *reinterpret_cast<const bf16x8*>(qp);
    const bf16x8 qf1 = *reinterpret_cast<const bf16x8*>(qp + 32);

    f32x4 acc[4];
#pragma unroll
    for (int nf = 0; nf < 4; ++nf) acc[nf] = f32x4{0.f, 0.f, 0.f, 0.f};

    const int njs = (t0 + 15) / 64 + 1;
    bf16x8 kf[4][2];
    int js = w;
    if (js < njs) {
      const int s0 = js * 64;
#pragma unroll
      for (int jf = 0; jf < 4; ++jf) {
        const u16* kp = kb + (bT + s0 + 16 * jf + l15) * 64 + 8 * l4;
        kf[jf][0] = *reinterpret_cast<const bf16x8*>(kp);
        kf[jf][1] = *reinterpret_cast<const bf16x8*>(kp + 32);
      }
    }
    for (; js < njs; js += 8) {
      const int s0 = js * 64;
      // vhat frags: issued now, consumed after the P LDS round-trip
      bf16x8 vf[4][2];
#pragma unroll
      for (int nf = 0; nf < 4; ++nf) {
        const u16* vp = vt + (size_t)(b * 64 + 16 * nf + l15) * kT + s0 + 8 * l4;
        vf[nf][0] = *reinterpret_cast<const bf16x8*>(vp);
        vf[nf][1] = *reinterpret_cast<const bf16x8*>(vp + 32);
      }
      // QK^T -> P -> wave-private LDS
#pragma unroll
      for (int jf = 0; jf < 4; ++jf) {
        f32x4 d = f32x4{0.f, 0.f, 0.f, 0.f};
        d = mfma16(qf0, kf[jf][0], d);
        d = mfma16(qf1, kf[jf][1], d);
        const int s = s0 + 16 * jf + l15;
#pragma unroll
        for (int r = 0; r < 4; ++r) {
          const int rr = 4 * l4 + r;
          const float p = (t0 + rr >= s) ? __expf(d[r] * kScale) : 0.f;
          pl[w][(rr * 64 + 16 * jf + l15) ^ ((rr & 7) << 3)] = f2bu(p);
        }
      }
      // prefetch next iteration's k-frags
      const int jn = js + 8;
      if (jn < njs) {
        const int sn = jn * 64;
#pragma unroll
        for (int jf = 0; jf < 4; ++jf) {
          const u16* kp = kb + (bT + sn + 16 * jf + l15) * 64 + 8 * l4;
          kf[jf][0] = *reinterpret_cast<const bf16x8*>(kp);
          kf[jf][1] = *reinterpret_cast<const bf16x8*>(kp + 32);
        }
      }
      // PV
      const bf16x8 pa0 = *reinterpret_cast<const bf16x8*>(
          &pl[w][(l15 * 64 + 8 * l4) ^ ((l15 & 7) << 3)]);
      const bf16x8 pa1 = *reinterpret_cast<const bf16x8*>(
          &pl[w][(l15 * 64 + 32 + 8 * l4) ^ ((l15 & 7) << 3)]);
#pragma unroll
      for (int nf = 0; nf < 4; ++nf) {
        acc[nf] = mfma16(pa0, vf[nf][0], acc[nf]);
        acc[nf] = mfma16(pa1, vf[nf][1], acc[nf]);
      }
    }
    // deterministic cross-wave reduce
#pragma unroll
    for (int nf = 0; nf < 4; ++nf) {
#pragma unroll
      for (int r = 0; r < 4; ++r) red[w][4 * l4 + r][16 * nf + l15] = acc[nf][r];
    }
    __syncthreads();
#pragma unroll
    for (int i = 0; i < 2; ++i) {
      const int idx = tid + 512 * i;
      const int r = idx >> 6, h = idx & 63;
      float sum = red[0][r][h];
#pragma unroll
      for (int ww = 1; ww < 8; ++ww) sum += red[ww][r][h];
      out[(bT + t0 + r) * 64 + h] = sum;
    }
    __syncthreads();  // protect red before next half rewrites it
  }
}

}  // namespace

extern "C" void kernel_launch(void* const* d_in, const int* in_sizes, int n_in,
                              void* d_out, int out_size, void* d_ws, size_t ws_size,
                              hipStream_t stream) {
  const float* x = (const float*)d_in[0];
  const float* Wk = (const float*)d_in[1];
  const float* Wq = (const float*)d_in[2];
  const float* Wv = (const float*)d_in[3];
  u16* wsu = (u16*)d_ws;
  u16* Wt = wsu + kWtOff;
  u16* qb = wsu + kQbOff;
  u16* kb = wsu + kKbOff;
  u16* vt = wsu + kVtOff;
  float* lG = (float*)(wsu + kLOff);
  float* out = (float*)d_out;

  hipMemsetAsync(lG, 0, kB * kT * sizeof(float), stream);
  wt_kernel<<<dim3(16, 3), dim3(256), 0, stream>>>(Wk, Wq, Wv, Wt);
  qkv_kernel<<<dim3(kB * kT / 32), dim3(256), 0, stream>>>(x, Wt, qb, kb, vt);
  colsum_kernel<<<dim3(kT / 64, 4, kB), dim3(256), 0, stream>>>(qb, kb, lG);
  vscale_kernel<<<dim3(512), dim3(256), 0, stream>>>(vt, lG);
  out_kernel<<<dim3(64, kB), dim3(512), 0, stream>>>(qb, kb, vt, out);
}